// Round 4
// baseline (221.374 us; speedup 1.0000x reference)
//
#include <hip/hip_runtime.h>

#define HW 4096  // 64*64 spatial

// Static device scratch (24 MiB): qkv[m][b][o][h][w] fp32, m in {0:q,1:k,2:v}.
// Fully rewritten by qkv_proj before attn reads it on every launch -> graph-safe.
__device__ float g_qkv[3 * 8 * 64 * HW];

#if __has_builtin(__builtin_amdgcn_exp2f)
#define QSCALE 1.4426950408889634f            // prescale q by log2(e); exp2 is native v_exp_f32
__device__ __forceinline__ float fexp(float l) { return __builtin_amdgcn_exp2f(l); }
#else
#define QSCALE 1.0f
__device__ __forceinline__ float fexp(float l) { return __expf(l); }
#endif

// qkv (R10, proven ~25us = 208 - attn 140 - fill 43): ZERO LDS. Lane = w
// column, x column in 64 VGPRs (coalesced b32 loads, vmcnt domain); W
// wave-uniform (readfirstlane) -> s_load_dwordx4 SGPR broadcasts (lgkmcnt
// domain, uncontended by any ds_read). 768 v_fmac v,s,v per thread.
// Grid 2048 = (os,b,h); wave owns o = os*16+wave*4..+3. Sibling os-blocks of
// one (b,h) are 512 apart (512%8==0 -> same XCD) so the 4x-re-read x row and
// broadcast W stay L2-resident. lb(256,2): 256-VGPR budget, no spill
// (demand ~90: xr 64 + acc 12 + addressing).
__global__ __launch_bounds__(256, 2) void qkv_proj(
    const float* __restrict__ x,
    const float* __restrict__ wq,
    const float* __restrict__ wk,
    const float* __restrict__ wv)
{
    const int t    = threadIdx.x;
    const int os   = blockIdx.x >> 9;          // o-slice 0..3
    const int b    = (blockIdx.x >> 6) & 7;
    const int h    = blockIdx.x & 63;
    const int lane = t & 63;                   // w column
    const int wave = __builtin_amdgcn_readfirstlane(t >> 6);
    const int obase = os * 16 + wave * 4;      // wave-uniform -> W addrs in SGPRs

    // x column -> 64 VGPRs. 64 coalesced global_load_dword (256B/line/wave).
    const float* __restrict__ xcol = x + (size_t)b * 64 * HW + (size_t)h * 64 + lane;
    float xr[64];
    #pragma unroll
    for (int c = 0; c < 64; ++c)
        xr[c] = xcol[(size_t)c * HW];

    const float* __restrict__ wmat[3] = { wq, wk, wv };
    float acc[3][4];
    #pragma unroll
    for (int m = 0; m < 3; ++m)
        #pragma unroll
        for (int oi = 0; oi < 4; ++oi) acc[m][oi] = 0.f;

    #pragma unroll
    for (int c0 = 0; c0 < 64; c0 += 4) {
        #pragma unroll
        for (int m = 0; m < 3; ++m)
            #pragma unroll
            for (int oi = 0; oi < 4; ++oi) {
                // uniform address -> s_load_dwordx4, operands stay in SGPRs
                const float4 wf = *(const float4*)&wmat[m][(obase + oi) * 64 + c0];
                acc[m][oi] = fmaf(wf.x, xr[c0 + 0], acc[m][oi]);
                acc[m][oi] = fmaf(wf.y, xr[c0 + 1], acc[m][oi]);
                acc[m][oi] = fmaf(wf.z, xr[c0 + 2], acc[m][oi]);
                acc[m][oi] = fmaf(wf.w, xr[c0 + 3], acc[m][oi]);
            }
    }

    #pragma unroll
    for (int m = 0; m < 3; ++m)
        #pragma unroll
        for (int oi = 0; oi < 4; ++oi)
            g_qkv[((size_t)(m * 8 + b) * 64 + obase + oi) * HW + (size_t)h * 64 + lane]
                = acc[m][oi];                  // b32 stores, lanes consecutive
}

// R11 attn: R9/R10 conflict-free column-per-lane mapping (verified: conflicts
// 2.09M -> 71K) + STRUCTURAL liveness cap. R10 still spilled (WRITE 180 MiB =
// 22x output, VGPR 128, VALUBusy 11%): the full 98-tap unroll let the
// scheduler hoist all 196 ds_read2 results -> ~240 live values > 256 budget
// -> allocator settles at 128 + wholesale scratch. Fix: consume one halo row
// (7 k + 7 v in named regs) at a time, then sched_barrier(0) -> max ~14
// in-flight LDS values, ~70-96 VGPR demand, zero scratch. Predicates stay
// compile-time: still 392 exp/thread (trans-pipe floor ~25us at DVFS clock).
// Block = (b,o,half): rows R0..R0+31, 38x70 halo (20.8 KB). Wave w owns pixel
// rows R0+8w..+7, all 64 cols; lane = pixel column -> LDS reads are 64
// consecutive dwords/wave = 2 lanes/bank = free.
// rel_w/rel_h dead (constant along 49-entry softmax axis -> shift-invariance).
// Zero padding + 1x1 conv => k=v=0 outside; logit q*0=0 still participates.
// k at kv[r][0..69], v at kv[r][70..139]: pair -> ds_read2_b32 offsets 0/70.
__global__ __launch_bounds__(256, 2) void attn(float* __restrict__ out)
{
    __shared__ float kv[38][140];     // 20.8 KB
    const int t  = threadIdx.x;
    const int hb = blockIdx.x >> 9;          // row half 0..1
    const int b  = (blockIdx.x >> 6) & 7;
    const int o  = blockIdx.x & 63;
    const int R0 = hb * 32;

    const float* qb = g_qkv + ((size_t)(0 * 8 + b) * 64 + o) * HW;
    const float* kb = g_qkv + ((size_t)(1 * 8 + b) * 64 + o) * HW;
    const float* vb = g_qkv + ((size_t)(2 * 8 + b) * 64 + o) * HW;

    const int c     = t & 63;         // pixel column = lane
    const int w     = t >> 6;         // wave 0..3
    const int rbase = w * 8;          // pixel row base within half

    // q column strip first: 8 coalesced b32 loads, overlap with staging.
    float qv[8];
    #pragma unroll
    for (int i = 0; i < 8; ++i)
        qv[i] = qb[(size_t)(R0 + rbase + i) * 64 + c] * QSCALE;

    for (int i = t; i < 38 * 70; i += 256) {
        int r = i / 70, cc = i - r * 70;
        int gh = R0 + r - 3, gw = cc - 3;
        float kk = 0.f, vv = 0.f;
        if ((unsigned)gh < 64u && (unsigned)gw < 64u) {
            kk = kb[gh * 64 + gw];
            vv = vb[gh * 64 + gw];
        }
        kv[r][cc] = kk;
        kv[r][70 + cc] = vv;
    }
    __syncthreads();

    float den[8], num[8];
    #pragma unroll
    for (int i = 0; i < 8; ++i) { den[i] = 0.f; num[i] = 0.f; }

    // Halo rows for this wave's strip: array rows rbase..rbase+13.
    // Pixel i (row rbase+i) active at tap hrl iff hrl-i in [0,7).
    // Column taps: pixel col c uses halo cols c..c+6 (all 7 always active).
    // One halo row per group; sched_barrier(0) forbids cross-group hoisting.
    #pragma unroll
    for (int hrl = 0; hrl < 14; ++hrl) {
        float kk[7], vv[7];
        #pragma unroll
        for (int dc = 0; dc < 7; ++dc) {
            kk[dc] = kv[rbase + hrl][c + dc];        // pair -> ds_read2_b32
            vv[dc] = kv[rbase + hrl][70 + c + dc];
        }
        #pragma unroll
        for (int dc = 0; dc < 7; ++dc) {
            #pragma unroll
            for (int i = 0; i < 8; ++i) {
                if (hrl - i >= 0 && hrl - i < 7) {   // compile-time predicates
                    float e = fexp(qv[i] * kk[dc]);
                    den[i] += e;
                    num[i] = fmaf(e, vv[dc], num[i]);
                }
            }
        }
        __builtin_amdgcn_sched_barrier(0);           // cap live LDS results at 14
    }

    float* ob = out + ((size_t)(b * 64 + o)) * HW;
    #pragma unroll
    for (int i = 0; i < 8; ++i)
        ob[(size_t)(R0 + rbase + i) * 64 + c] = num[i] / den[i];
}

extern "C" void kernel_launch(void* const* d_in, const int* in_sizes, int n_in,
                              void* d_out, int out_size, void* d_ws, size_t ws_size,
                              hipStream_t stream)
{
    // d_in: 0=x, 1=wq, 2=wk, 3=wv (fp32), 4=rel_w, 5=rel_h (dead: softmax
    // shift-invariance), 6=kernel_size(7), 7=padding(3) hardcoded.
    qkv_proj<<<dim3(2048), dim3(256), 0, stream>>>(
        (const float*)d_in[0], (const float*)d_in[1],
        (const float*)d_in[2], (const float*)d_in[3]);
    attn<<<dim3(1024), dim3(256), 0, stream>>>((float*)d_out);
}

// Round 5
// 218.048 us; speedup vs baseline: 1.0153x; 1.0153x over previous
//
#include <hip/hip_runtime.h>

#define HW 4096  // 64*64 spatial

// Static device scratch (24 MiB): qkv[m][b][o][h][w] fp32, m in {0:q,1:k,2:v}.
// Fully rewritten by qkv_proj before attn reads it on every launch -> graph-safe.
__device__ float g_qkv[3 * 8 * 64 * HW];

#if __has_builtin(__builtin_amdgcn_exp2f)
#define QSCALE 1.4426950408889634f            // prescale q by log2(e); exp2 is native v_exp_f32
__device__ __forceinline__ float fexp(float l) { return __builtin_amdgcn_exp2f(l); }
#else
#define QSCALE 1.0f
__device__ __forceinline__ float fexp(float l) { return __expf(l); }
#endif

// qkv (R10/R11, unchanged for isolation): ZERO LDS. Lane = w column, x column
// in 64 VGPRs (coalesced b32 loads, vmcnt domain); W wave-uniform
// (readfirstlane) -> s_load_dwordx4 SGPR broadcasts (lgkmcnt domain,
// uncontended by any ds_read). 768 v_fmac v,s,v per thread.
// Grid 2048 = (os,b,h); wave owns o = os*16+wave*4..+3. Sibling os-blocks of
// one (b,h) are 512 apart (512%8==0 -> same XCD) so the 4x-re-read x row and
// broadcast W stay L2-resident. lb(256,2): 256-VGPR budget, no spill
// (demand ~90: xr 64 + acc 12 + addressing).
__global__ __launch_bounds__(256, 2) void qkv_proj(
    const float* __restrict__ x,
    const float* __restrict__ wq,
    const float* __restrict__ wk,
    const float* __restrict__ wv)
{
    const int t    = threadIdx.x;
    const int os   = blockIdx.x >> 9;          // o-slice 0..3
    const int b    = (blockIdx.x >> 6) & 7;
    const int h    = blockIdx.x & 63;
    const int lane = t & 63;                   // w column
    const int wave = __builtin_amdgcn_readfirstlane(t >> 6);
    const int obase = os * 16 + wave * 4;      // wave-uniform -> W addrs in SGPRs

    // x column -> 64 VGPRs. 64 coalesced global_load_dword (256B/line/wave).
    const float* __restrict__ xcol = x + (size_t)b * 64 * HW + (size_t)h * 64 + lane;
    float xr[64];
    #pragma unroll
    for (int c = 0; c < 64; ++c)
        xr[c] = xcol[(size_t)c * HW];

    const float* __restrict__ wmat[3] = { wq, wk, wv };
    float acc[3][4];
    #pragma unroll
    for (int m = 0; m < 3; ++m)
        #pragma unroll
        for (int oi = 0; oi < 4; ++oi) acc[m][oi] = 0.f;

    #pragma unroll
    for (int c0 = 0; c0 < 64; c0 += 4) {
        #pragma unroll
        for (int m = 0; m < 3; ++m)
            #pragma unroll
            for (int oi = 0; oi < 4; ++oi) {
                // uniform address -> s_load_dwordx4, operands stay in SGPRs
                const float4 wf = *(const float4*)&wmat[m][(obase + oi) * 64 + c0];
                acc[m][oi] = fmaf(wf.x, xr[c0 + 0], acc[m][oi]);
                acc[m][oi] = fmaf(wf.y, xr[c0 + 1], acc[m][oi]);
                acc[m][oi] = fmaf(wf.z, xr[c0 + 2], acc[m][oi]);
                acc[m][oi] = fmaf(wf.w, xr[c0 + 3], acc[m][oi]);
            }
    }

    #pragma unroll
    for (int m = 0; m < 3; ++m)
        #pragma unroll
        for (int oi = 0; oi < 4; ++oi)
            g_qkv[((size_t)(m * 8 + b) * 64 + obase + oi) * HW + (size_t)h * 64 + lane]
                = acc[m][oi];                  // b32 stores, lanes consecutive
}

// R12 attn: SPILL-PROOF by construction. R11 still spilled (VGPR 128, WRITE
// 186 MiB = 23x output) despite sched_barrier: group liveness (24 acc + 14
// taps + ~56 trans-pipe exp temps) sat at the 128 edge and the allocator
// spilled wholesale. R9->R10 showed phantom traffic exactly halves when VGPR
// doubles -> spill. Fix: halve per-thread state. 512 threads / 8 waves per
// block; wave owns a 4-ROW strip (rows 4w..4w+3), lane = pixel column (LDS
// reads stay 64 consecutive dwords/wave = conflict-free, verified 71K).
// Per-thread demand: qv[4]+den[4]+num[4]=12 + 14 taps + ~28 temps ~= 60 regs
// vs lb(512,4) budget 128 (2 blocks/CU = 16 waves/CU, 2x R11 occupancy).
// exp/thread = 4 rows x 49 = 196 (optimal, total unchanged). LDS ops/px
// 12.25 -> 17.5 (+43%) -- cheap, conflict-free with unit headroom.
// Block = (b,o,half): rows R0..R0+31, 38x70 halo (20.8 KB). Halves of one
// (b,o) sit 512 apart (512%8==0 -> same XCD slot), shared halo rows L2-hit.
// rel_w/rel_h dead (constant along 49-entry softmax axis -> shift-invariance).
// Zero padding + 1x1 conv => k=v=0 outside; logit q*0=0 still participates.
// k at kv[r][0..69], v at kv[r][70..139]: pair -> ds_read2_b32 offsets 0/70.
__global__ __launch_bounds__(512, 4) void attn(float* __restrict__ out)
{
    __shared__ float kv[38][140];     // 20.8 KB
    const int t  = threadIdx.x;
    const int hb = blockIdx.x >> 9;          // row half 0..1
    const int b  = (blockIdx.x >> 6) & 7;
    const int o  = blockIdx.x & 63;
    const int R0 = hb * 32;

    const float* qb = g_qkv + ((size_t)(0 * 8 + b) * 64 + o) * HW;
    const float* kb = g_qkv + ((size_t)(1 * 8 + b) * 64 + o) * HW;
    const float* vb = g_qkv + ((size_t)(2 * 8 + b) * 64 + o) * HW;

    const int c     = t & 63;         // pixel column = lane
    const int w     = t >> 6;         // wave 0..7
    const int rbase = w * 4;          // pixel row base within half (0..28)

    // q column strip first: 4 coalesced b32 loads, overlap with staging.
    float qv[4];
    #pragma unroll
    for (int i = 0; i < 4; ++i)
        qv[i] = qb[(size_t)(R0 + rbase + i) * 64 + c] * QSCALE;

    for (int i = t; i < 38 * 70; i += 512) {
        int r = i / 70, cc = i - r * 70;
        int gh = R0 + r - 3, gw = cc - 3;
        float kk = 0.f, vv = 0.f;
        if ((unsigned)gh < 64u && (unsigned)gw < 64u) {
            kk = kb[gh * 64 + gw];
            vv = vb[gh * 64 + gw];
        }
        kv[r][cc] = kk;
        kv[r][70 + cc] = vv;
    }
    __syncthreads();

    float den[4], num[4];
    #pragma unroll
    for (int i = 0; i < 4; ++i) { den[i] = 0.f; num[i] = 0.f; }

    // Halo rows for this wave's strip: array rows rbase..rbase+9 (10 rows).
    // Pixel i (row rbase+i) active at tap hrl iff hrl-i in [0,7).
    // Column taps: pixel col c uses halo cols c..c+6 (all 7 always active).
    // One halo row per group; sched_barrier(0) bounds the hoisting window.
    #pragma unroll
    for (int hrl = 0; hrl < 10; ++hrl) {
        float kk[7], vv[7];
        #pragma unroll
        for (int dc = 0; dc < 7; ++dc) {
            kk[dc] = kv[rbase + hrl][c + dc];        // pair -> ds_read2_b32
            vv[dc] = kv[rbase + hrl][70 + c + dc];
        }
        #pragma unroll
        for (int dc = 0; dc < 7; ++dc) {
            #pragma unroll
            for (int i = 0; i < 4; ++i) {
                if (hrl - i >= 0 && hrl - i < 7) {   // compile-time predicates
                    float e = fexp(qv[i] * kk[dc]);
                    den[i] += e;
                    num[i] = fmaf(e, vv[dc], num[i]);
                }
            }
        }
        __builtin_amdgcn_sched_barrier(0);           // cap live LDS results at 14
    }

    float* ob = out + ((size_t)(b * 64 + o)) * HW;
    #pragma unroll
    for (int i = 0; i < 4; ++i)
        ob[(size_t)(R0 + rbase + i) * 64 + c] = num[i] / den[i];
}

extern "C" void kernel_launch(void* const* d_in, const int* in_sizes, int n_in,
                              void* d_out, int out_size, void* d_ws, size_t ws_size,
                              hipStream_t stream)
{
    // d_in: 0=x, 1=wq, 2=wk, 3=wv (fp32), 4=rel_w, 5=rel_h (dead: softmax
    // shift-invariance), 6=kernel_size(7), 7=padding(3) hardcoded.
    qkv_proj<<<dim3(2048), dim3(256), 0, stream>>>(
        (const float*)d_in[0], (const float*)d_in[1],
        (const float*)d_in[2], (const float*)d_in[3]);
    attn<<<dim3(1024), dim3(512), 0, stream>>>((float*)d_out);
}

// Round 6
// 157.371 us; speedup vs baseline: 1.4067x; 1.3856x over previous
//
#include <hip/hip_runtime.h>

#define HW 4096  // 64*64 spatial

#if __has_builtin(__builtin_amdgcn_exp2f)
#define QSCALE 1.4426950408889634f            // prescale q by log2(e); exp2 is native v_exp_f32
__device__ __forceinline__ float fexp(float l) { return __builtin_amdgcn_exp2f(l); }
#else
#define QSCALE 1.0f
__device__ __forceinline__ float fexp(float l) { return __expf(l); }
#endif

// R13: FULLY FUSED — g_qkv deleted. R9-R12 showed both kernels were dominated
// by moving the 24 MB intermediate: attn's phantom TCC traffic scaled with
// occupancy (R9/R12 occ 42-45% -> 185/350 MB; R10/R11 occ 22% -> 102/187 MB),
// i.e. concurrent (b,o)-slices churning L2, NOT register spill (R12: VGPR 64,
// demand ~45, traffic unchanged). And qkv was ~87us (218-131), not 25: its 192
// wave-uniform s_load_dwordx4 thrash the scalar cache at 2 waves/SIMD.
// Real work is tiny (~6us FMA + ~5us exp) — so fuse and keep everything local.
//
// Block = (b, o-pair, row-half): grid 512 = 8b x 32og x 2half, 512 threads,
// 2 blocks/CU exactly. b = blockIdx%8 -> XCD i sees only b=i, so x[b] (1 MB)
// is L2-resident and shared by that XCD's 64 blocks. Global traffic: x 8 MB +
// W 48 KB + out 8 MB. Phases:
//  1) stage W for o0,o0+1 into LDS (384 floats; read in GEMM as wave-uniform
//     LDS broadcasts — conflict-free, no scalar-cache dependence);
//  2) GEMM in regs: warp j owns halo rows {j+8s, s<5} (38 rows total), lane=w.
//     Per channel c: 5 row-guarded coalesced x loads (zero outside image ->
//     k=v=0 pad semantics), 6 ds_read_b64 weight broadcasts, 28 FMA.
//     q rows (halo rows 3..34) reuse the SAME x values -> no extra loads;
//  3) write k/v (38x64 + zeroed 3-col pads) and q*QSCALE to LDS;
//  4) attention = R12's proven conflict-free phase: warp j owns pixel rows
//     4j..4j+3, lane = col; taps kv[g][4j+hrl][lane+dc] = 64 consecutive
//     dwords/wave (2 lanes/bank = free); 392 exp/thread.
// rel_w/rel_h dead (constant along the 49-entry softmax axis).
// LDS: wl 1.5K + kv 2x38x140 = 41.6K + qs 2x32x64 = 16K -> 60.5 KB.
// Liveness ~80 regs (acc 30 + xv 10 + ptrs/misc) vs lb(512,4) budget 128:
// spill-proof. No device globals -> trivially graph-safe.
__global__ __launch_bounds__(512, 4) void fused_attn(
    const float* __restrict__ x,
    const float* __restrict__ wq,
    const float* __restrict__ wk,
    const float* __restrict__ wv,
    float* __restrict__ out)
{
    __shared__ float wl[2][3][64];       // [g][m][c], m: 0=q,1=k,2=v
    __shared__ float kv[2][38][140];     // k cols 0..69 (halo -3..66), v +70
    __shared__ float qs[2][32][64];      // q * QSCALE

    const int t    = threadIdx.x;
    const int lane = t & 63;             // w / pixel column
    const int j    = t >> 6;             // warp 0..7
    const int b    = blockIdx.x & 7;                 // XCD pin
    const int o0   = ((blockIdx.x >> 3) & 31) * 2;   // o pair base
    const int R0   = ((blockIdx.x >> 8) & 1) * 32;   // row half base

    // ---- stage weights (one shot, 384 floats) ----
    if (t < 384) {
        const int g = t / 192, m = (t / 64) % 3, c = t & 63;
        const float* __restrict__ ws = (m == 0) ? wq : (m == 1) ? wk : wv;
        wl[g][m][c] = ws[(o0 + g) * 64 + c];
    }
    // ---- zero the 3-col halo pads (cols 0..2,67..69 of k; +70 for v) ----
    for (int i = t; i < 2 * 38 * 12; i += 512) {
        const int g = i / 456, r = (i % 456) / 12, u = i % 12;
        const int part = u / 6, uu = u % 6;
        kv[g][r][part * 70 + (uu < 3 ? uu : uu + 64)] = 0.f;
    }

    // ---- per-thread halo-row slots ----
    int  hr[5]; bool sval[5], ldv[5], qval[5];
    const float* __restrict__ xp[5];
    const float* __restrict__ xb = x + (size_t)b * 64 * HW;
    #pragma unroll
    for (int s = 0; s < 5; ++s) {
        hr[s]   = j + 8 * s;
        sval[s] = hr[s] < 38;                        // row exists in LDS
        const int grm = R0 + hr[s] - 3;              // global image row
        ldv[s]  = (unsigned)grm < 64u;               // safe+nonzero to load
        qval[s] = sval[s] && hr[s] >= 3 && hr[s] <= 34;   // is a pixel row
        xp[s]   = xb + (size_t)(ldv[s] ? grm : 0) * 64 + lane;
    }

    float kacc[5][2], vacc[5][2], qacc[5][2];
    #pragma unroll
    for (int s = 0; s < 5; ++s)
        #pragma unroll
        for (int g = 0; g < 2; ++g) {
            kacc[s][g] = 0.f; vacc[s][g] = 0.f; qacc[s][g] = 0.f;
        }

    __syncthreads();     // wl ready (pads done too)

    // ---- GEMM: c-chunks of 2, bounded liveness (10 xv in flight) ----
    #pragma unroll 2
    for (int c0 = 0; c0 < 64; c0 += 2) {
        float xv[5][2];
        #pragma unroll
        for (int s = 0; s < 5; ++s)
            #pragma unroll
            for (int cc = 0; cc < 2; ++cc)
                xv[s][cc] = ldv[s] ? xp[s][(size_t)(c0 + cc) * HW] : 0.f;
        #pragma unroll
        for (int g = 0; g < 2; ++g) {
            const float2 wqc = *(const float2*)&wl[g][0][c0];   // broadcast b64
            const float2 wkc = *(const float2*)&wl[g][1][c0];
            const float2 wvc = *(const float2*)&wl[g][2][c0];
            #pragma unroll
            for (int s = 0; s < 5; ++s) {            // s=4 garbage on j>=6: never stored
                kacc[s][g] = fmaf(wkc.x, xv[s][0], kacc[s][g]);
                kacc[s][g] = fmaf(wkc.y, xv[s][1], kacc[s][g]);
                vacc[s][g] = fmaf(wvc.x, xv[s][0], vacc[s][g]);
                vacc[s][g] = fmaf(wvc.y, xv[s][1], vacc[s][g]);
                qacc[s][g] = fmaf(wqc.x, xv[s][0], qacc[s][g]);
                qacc[s][g] = fmaf(wqc.y, xv[s][1], qacc[s][g]);
            }
        }
    }

    // ---- commit k/v/q to LDS ----
    #pragma unroll
    for (int s = 0; s < 5; ++s) {
        if (sval[s]) {
            #pragma unroll
            for (int g = 0; g < 2; ++g) {
                kv[g][hr[s]][3 + lane]  = kacc[s][g];   // zeros if row OOB ✓
                kv[g][hr[s]][73 + lane] = vacc[s][g];
            }
        }
        if (qval[s]) {
            #pragma unroll
            for (int g = 0; g < 2; ++g)
                qs[g][hr[s] - 3][lane] = qacc[s][g] * QSCALE;
        }
    }
    __syncthreads();

    // ---- attention (R12-proven conflict-free mapping) ----
    #pragma unroll
    for (int g = 0; g < 2; ++g) {
        float qv4[4];
        #pragma unroll
        for (int i = 0; i < 4; ++i)
            qv4[i] = qs[g][4 * j + i][lane];            // row uniform, 64 consec
        float den[4], num[4];
        #pragma unroll
        for (int i = 0; i < 4; ++i) { den[i] = 0.f; num[i] = 0.f; }

        // pixel row p=4j+i taps halo rows p..p+6 -> rows 4j..4j+9
        #pragma unroll
        for (int hrl = 0; hrl < 10; ++hrl) {
            float kk[7], vv[7];
            #pragma unroll
            for (int dc = 0; dc < 7; ++dc) {
                kk[dc] = kv[g][4 * j + hrl][lane + dc];       // ds_read2 pair
                vv[dc] = kv[g][4 * j + hrl][70 + lane + dc];
            }
            #pragma unroll
            for (int dc = 0; dc < 7; ++dc) {
                #pragma unroll
                for (int i = 0; i < 4; ++i) {
                    if (hrl - i >= 0 && hrl - i < 7) {        // compile-time
                        float e = fexp(qv4[i] * kk[dc]);
                        den[i] += e;
                        num[i] = fmaf(e, vv[dc], num[i]);
                    }
                }
            }
            __builtin_amdgcn_sched_barrier(0);                // cap liveness
        }

        float* __restrict__ ob = out + ((size_t)(b * 64 + o0 + g)) * HW;
        #pragma unroll
        for (int i = 0; i < 4; ++i)
            ob[(size_t)(R0 + 4 * j + i) * 64 + lane] = num[i] / den[i];
    }
}

extern "C" void kernel_launch(void* const* d_in, const int* in_sizes, int n_in,
                              void* d_out, int out_size, void* d_ws, size_t ws_size,
                              hipStream_t stream)
{
    // d_in: 0=x, 1=wq, 2=wk, 3=wv (fp32), 4=rel_w, 5=rel_h (dead: softmax
    // shift-invariance), 6=kernel_size(7), 7=padding(3) hardcoded.
    fused_attn<<<dim3(512), dim3(512), 0, stream>>>(
        (const float*)d_in[0], (const float*)d_in[1],
        (const float*)d_in[2], (const float*)d_in[3],
        (float*)d_out);
}